// Round 13
// baseline (247.814 us; speedup 1.0000x reference)
//
#include <hip/hip_runtime.h>
#include <hip/hip_bf16.h>

// Problem constants
#define BB 4
#define CC 768
#define CT 192
#define TT 2048
#define SS 1024
#define KK 12

typedef __attribute__((ext_vector_type(8))) short bfrag8;  // 8 bf16 = 4 VGPR
typedef __attribute__((ext_vector_type(4))) float f32x4;

// ---------------------------------------------------------------------------
// Fragment-layout convention (16x16x32 bf16 MFMA):
//   A: row m = lane&15, k-slot = 32*cc + (lane>>4)*8 + j
//   B: col n = lane&15, k-slot = 32*cc + (lane>>4)*8 + j
//   D: col n = lane&15, row m = (lane>>4)*4 + reg   (HW-verified)
//
// HARD CONSTRAINTS (measured R7-R12):
//  - arch-VGPR budget pinned at 128; live sets must stay <=~120.
//  - R12: 146KB LDS -> 1 block/CU -> 2 waves/SIMD -> L2 latency exposed.
// R13: attn LDS cut to ~67KB (drop head-pairing's 64KB exp_buf; exp lives in
// accv regs, R5-proven) -> 2 blocks/CU, 4 waves/SIMD. textS L2 doubles to
// 2.4GB (~68us BW floor) but latency-hiding doubles and barriers overlap.
// ---------------------------------------------------------------------------

__device__ inline unsigned pk2(float a, float b) {
    __hip_bfloat162 h2;
    h2.x = __float2bfloat16(a);
    h2.y = __float2bfloat16(b);
    return *reinterpret_cast<unsigned*>(&h2);
}

// ---------------------------------------------------------------------------
// ONE pack kernel, 512 blocks:
//   blk 0..31   : textS/textC  (b = blk>>3, part = blk&7)
//   blk 32..127 : WP           (k = (blk-32)>>3, part = (blk-32)&7)
//   blk 128..255: yP via LDS transpose (b = idx>>5, tq = idx&31; 64 t each)
//   blk 256..511: yb[k,b,t] = sum_o y*bias (b = idx>>6, 32-t chunk idx&63)
// Branch uniform per block; LDS is a 48K union (per-branch views).
// ---------------------------------------------------------------------------
__global__ __launch_bounds__(256) void k_pack_all(
    const float* __restrict__ text, const float* __restrict__ W,
    const float* __restrict__ y, const float* __restrict__ bias,
    __hip_bfloat16* __restrict__ textS, __hip_bfloat16* __restrict__ textC,
    __hip_bfloat16* __restrict__ WP, __hip_bfloat16* __restrict__ yP,
    float* __restrict__ ybws) {
    __shared__ __align__(16) char pk_lds[49152];  // union
    const int blk = blockIdx.x;
    const int tid = threadIdx.x;

    if (blk < 32) {
        const int b = blk >> 3;
        const float* tb = text + (size_t)b * CT * SS;
        const int base = tid + (blk & 7) * 256;
        for (int e = base; e < 64 * 6 * 512; e += 2048) {
            int jj = e & 7, l = (e >> 3) & 63, cc = (e >> 9) % 6, st = e / 3072;
            int ct = cc * 32 + ((l >> 4) << 3) + jj;
            int s = st * 16 + (l & 15);
            textS[(size_t)b * 196608 + e] =
                __float2bfloat16(tb[(size_t)ct * SS + s]);
        }
        for (int e = base; e < 12 * 32 * 512; e += 2048) {
            int jj = e & 7, l = (e >> 3) & 63, scg = (e >> 9) & 31,
                ctt = e / 16384;
            int ct = ctt * 16 + (l & 15);
            int s = scg * 32 + ((l >> 4) << 3) + jj;
            textC[(size_t)b * 196608 + e] =
                __float2bfloat16(tb[(size_t)ct * SS + s]);
        }
    } else if (blk < 128) {
        const int k = (blk - 32) >> 3;
        const float* wk = W + (size_t)k * CC * CT;
        const int base = tid + ((blk - 32) & 7) * 256;
        for (int e = base; e < 12 * 24 * 512; e += 2048) {
            int j = e & 7, l = (e >> 3) & 63, oc = (e >> 9) % 24, nt = e / 12288;
            int ct = nt * 16 + (l & 15);
            int o = oc * 32 + ((l >> 4) << 3) + j;
            WP[(size_t)k * 147456 + e] =
                __float2bfloat16(wk[(size_t)o * CT + ct]);
        }
    } else if (blk < 256) {
        float(*tile)[64] = reinterpret_cast<float(*)[64]>(pk_lds);  // 8K
        const int idx = blk - 128;
        const int b = idx >> 5;
        const int tq = idx & 31;
        const int t0 = tq * 64;
        const float* yb_ = y + (size_t)b * CC * TT;
        const int w = tid >> 6, l = tid & 63;
        const int l15 = l & 15, lg = l >> 4;
        const int row0 = tid >> 4;
        const int c4 = tid & 15;

        for (int oc = 0; oc < 24; ++oc) {
#pragma unroll
            for (int h = 0; h < 2; ++h) {
                const int row = row0 + h * 16;
                const float4 v = *reinterpret_cast<const float4*>(
                    yb_ + (size_t)(oc * 32 + row) * TT + t0 + c4 * 4);
                *reinterpret_cast<float4*>(&tile[row][c4 * 4]) = v;
            }
            __syncthreads();
            union {
                bfrag8 v8;
                short u[8];
            } A;
#pragma unroll
            for (int j = 0; j < 8; ++j)
                A.u[j] = (short)__bfloat16_as_ushort(
                    __float2bfloat16(tile[lg * 8 + j][w * 16 + l15]));
            __hip_bfloat16* dst =
                yP + (((size_t)(b * 128 + tq * 4 + w) * 24 + oc) * 512) +
                (size_t)l * 8;
            *reinterpret_cast<bfrag8*>(dst) = A.v8;
            __syncthreads();
        }
    } else {
        // yb: b = idx>>6, 32-t chunk = idx&63
        float(*bs)[CC] = reinterpret_cast<float(*)[CC]>(pk_lds);  // 36K
        float(*pb)[32][KK] =
            reinterpret_cast<float(*)[32][KK]>(pk_lds + 36864);   // 12K
        const int idx = blk - 256;
        const int b = idx >> 6;
        const int t0 = (idx & 63) * 32;
        const int tl = tid & 31, g = tid >> 5;  // 8 groups x 96 o

        for (int i = tid; i < KK * CC; i += 256) bs[i / CC][i % CC] = bias[i];
        __syncthreads();

        float p[KK];
#pragma unroll
        for (int k = 0; k < KK; ++k) p[k] = 0.f;
        const float* yb_ = y + (size_t)b * CC * TT + t0 + tl;
        for (int o = g * 96; o < g * 96 + 96; ++o) {
            float v = yb_[(size_t)o * TT];
#pragma unroll
            for (int k = 0; k < KK; ++k) p[k] += v * bs[k][o];
        }
#pragma unroll
        for (int k = 0; k < KK; ++k) pb[g][tl][k] = p[k];
        __syncthreads();
        for (int i = tid; i < 32 * KK; i += 256) {
            int t = i / KK, k = i % KK;
            float s = 0.f;
#pragma unroll
            for (int gg = 0; gg < 8; ++gg) s += pb[gg][t][k];
            ybws[((size_t)k * BB + b) * TT + t0 + t] = s;
        }
    }
}

// ---------------------------------------------------------------------------
// yW via MFMA. 1536 blocks, XCD b-affinity swizzle, wave = 3 nt x 4 ttg.
// R13: 2-deep double-buffer on af/bf (oc+1 loads issued before oc's MFMAs
// retire) -> L2 latency hidden in-wave. Regs: acc 48 + af 32 + bf 24 ~= 114.
// Epilogue via padded-LDS bounce -> b128 stores (R10, proven).
// ---------------------------------------------------------------------------
__global__ __launch_bounds__(256, 2) void k_yw_mfma(
    const __hip_bfloat16* __restrict__ yP, const __hip_bfloat16* __restrict__ WP,
    __hip_bfloat16* __restrict__ ywA) {
    const int i = blockIdx.x;
    const int x = i & 7, j = i >> 3;
    const int b = x & 3;
    const int k = j >> 4;
    const int tx = (j & 15) | ((x >> 2) << 4);
    const int kb = k * BB + b;

    const int tid = threadIdx.x;
    const int w = tid >> 6, l = tid & 63;
    const int l15 = l & 15, lg = l >> 4;
    const int ttg0 = tx * 4;
    const int nt0 = 3 * w;

    __shared__ float ot[4][16][197];  // 50.4 KB

    const short* ypb = reinterpret_cast<const short*>(yP) +
                       (((size_t)b * 128 + ttg0) * 24) * 512 + (size_t)l * 8;
    const short* wp = reinterpret_cast<const short*>(WP) +
                      (size_t)k * 147456 + (size_t)l * 8;

    f32x4 acc[3][4];
#pragma unroll
    for (int n = 0; n < 3; ++n)
#pragma unroll
        for (int tg = 0; tg < 4; ++tg) acc[n][tg] = (f32x4){0.f, 0.f, 0.f, 0.f};

    bfrag8 af[2][4], bf[2][3];
#pragma unroll
    for (int tg = 0; tg < 4; ++tg)
        af[0][tg] = *reinterpret_cast<const bfrag8*>(ypb + (tg * 24) * 512);
#pragma unroll
    for (int n = 0; n < 3; ++n)
        bf[0][n] = *reinterpret_cast<const bfrag8*>(wp + ((nt0 + n) * 24) * 512);

#pragma unroll
    for (int oc = 0; oc < 24; ++oc) {
        const int cur = oc & 1, nxt = cur ^ 1;
        if (oc < 23) {
#pragma unroll
            for (int tg = 0; tg < 4; ++tg)
                af[nxt][tg] = *reinterpret_cast<const bfrag8*>(
                    ypb + (tg * 24 + oc + 1) * 512);
#pragma unroll
            for (int n = 0; n < 3; ++n)
                bf[nxt][n] = *reinterpret_cast<const bfrag8*>(
                    wp + ((nt0 + n) * 24 + oc + 1) * 512);
        }
#pragma unroll
        for (int n = 0; n < 3; ++n)
#pragma unroll
            for (int tg = 0; tg < 4; ++tg)
                acc[n][tg] = __builtin_amdgcn_mfma_f32_16x16x32_bf16(
                    af[cur][tg], bf[cur][n], acc[n][tg], 0, 0, 0);
    }

#pragma unroll
    for (int n = 0; n < 3; ++n) {
        const int ct = (w * 3 + n) * 16 + l15;
#pragma unroll
        for (int tg = 0; tg < 4; ++tg)
#pragma unroll
            for (int r = 0; r < 4; ++r) ot[tg][lg * 4 + r][ct] = acc[n][tg][r];
    }
    __syncthreads();

    const size_t obase = ((size_t)kb * 128 + ttg0 + w) * 3072;
#pragma unroll
    for (int cc = 0; cc < 6; ++cc) {
        union {
            bfrag8 v8;
            short u[8];
        } A;
#pragma unroll
        for (int j2 = 0; j2 < 8; ++j2)
            A.u[j2] = (short)__bfloat16_as_ushort(
                __float2bfloat16(ot[w][l15][cc * 32 + lg * 8 + j2]));
        *reinterpret_cast<bfrag8*>(
            reinterpret_cast<short*>(ywA) + obase + cc * 512 + (size_t)l * 8) =
            A.v8;
    }
}

// ---------------------------------------------------------------------------
// FUSED attn, R13: single-head loop (exp in accv regs, accsum in regs —
// R5-proven 128-fit), af staged per head in LDS (6KB, keeps ywA dedup),
// textS bfc prefetch, exp2. LDS = 64K union (af_s | prob-dump | part) +
// lred ~1K + yb_s -> ~67KB => 2 blocks/CU, 4 waves/SIMD.
// Per head: stage-barrier + lred-barrier (24 total, overlapped across the
// 2 resident blocks).
// ---------------------------------------------------------------------------
__global__ __launch_bounds__(512) void k_attn_fused(
    const float* __restrict__ ymask, const float* __restrict__ tmask,
    const float* __restrict__ scale, const __hip_bfloat16* __restrict__ ywA,
    const float* __restrict__ ybws, const __hip_bfloat16* __restrict__ textS,
    const __hip_bfloat16* __restrict__ textC, const float* __restrict__ y,
    const float* __restrict__ ge, float* __restrict__ out) {
    const int i = blockIdx.x;
    const int x = i & 7;
    const int b = x & 3;
    const int tt = (i >> 3) + ((x >> 2) << 6);
    const int t0 = tt * 16;
    const int tid = threadIdx.x;
    const int w = tid >> 6;       // 0..7
    const int l = tid & 63;
    const int l15 = l & 15, lg = l >> 4;
    const int ws0 = w * 128;

    // 64K union: af_s (6KB) during head loop; prob-dump [8][8][64][4] f32
    // and part [4][16][192] f32 during ctx phase.
    __shared__ __align__(16) char lds_raw[65536];
    short(*af_s)[64][8] = reinterpret_cast<short(*)[64][8]>(lds_raw);
    float(*lds_acc)[8][64][4] = reinterpret_cast<float(*)[8][64][4]>(lds_raw);
    float(*part)[16][192] = reinterpret_cast<float(*)[16][192]>(lds_raw);

    __shared__ float yb_s[KK][16];
    __shared__ float sc_s[KK];
    __shared__ __align__(16) float lred[2][16][8];  // [k&1][row][w]

    if (tid < 192)
        yb_s[tid >> 4][tid & 15] =
            ybws[(size_t)((tid >> 4) * BB + b) * TT + t0 + (tid & 15)];
    if (tid < KK) sc_s[tid] = scale[tid];

    float tm2r[8];
#pragma unroll
    for (int st = 0; st < 8; ++st) {
        float m = tmask[b * SS + ws0 + st * 16 + l15];
        tm2r[st] = m * m;
    }
    float ymr[4];
#pragma unroll
    for (int r = 0; r < 4; ++r) ymr[r] = ymask[b * TT + t0 + lg * 4 + r];
    // 1/sqrt(768) * log2(e); exp(x) computed as exp2(x*log2e)
    const float invs_l2e = 0.03608439182435161f * 1.4426950408889634f;
    const f32x4 zero4 = (f32x4){0.f, 0.f, 0.f, 0.f};

    f32x4 accsum[8];
#pragma unroll
    for (int st = 0; st < 8; ++st) accsum[st] = zero4;

    const short* ywAs = reinterpret_cast<const short*>(ywA);
    const short* tS = reinterpret_cast<const short*>(textS);
    const short* tSw = tS + (((size_t)b * 64 + w * 8) * 6) * 512 + (size_t)l * 8;

    for (int k = 0; k < KK; ++k) {
        // stage this head's A-frags (shared by all 8 waves): 384 x 16B
        const size_t ab0 =
            (((size_t)(k * BB + b) * 128 + tt) * 6) * 512;
        if (tid < 384) {
            const int cc2 = tid >> 6, l2 = tid & 63;
            bfrag8 v = *reinterpret_cast<const bfrag8*>(ywAs + ab0 +
                                                        cc2 * 512 + l2 * 8);
            *reinterpret_cast<bfrag8*>(&af_s[cc2][l2][0]) = v;
        }
        __syncthreads();  // af_s ready; also covers yb_s/sc_s first use and
                          // lred[k&1] reuse (reads at k-2 precede this)

        const float sk = sc_s[k] * invs_l2e;
        float cfr[4], ybk[4];
#pragma unroll
        for (int r = 0; r < 4; ++r) {
            cfr[r] = sk * ymr[r];
            ybk[r] = yb_s[k][lg * 4 + r] * cfr[r];  // pre-scaled bias
        }

        // prime textS pipeline
        bfrag8 bfc[6];
#pragma unroll
        for (int cc = 0; cc < 6; ++cc)
            bfc[cc] = *reinterpret_cast<const bfrag8*>(tSw + cc * 512);

        f32x4 accv[8];
        float lrow[4] = {0.f, 0.f, 0.f, 0.f};
#pragma unroll
        for (int st = 0; st < 8; ++st) {
            f32x4 av = zero4;
            __builtin_amdgcn_s_setprio(1);
#pragma unroll
            for (int cc = 0; cc < 6; ++cc) {
                bfrag8 a0 =
                    *reinterpret_cast<const bfrag8*>(&af_s[cc][l][0]);
                av = __builtin_amdgcn_mfma_f32_16x16x32_bf16(a0, bfc[cc], av,
                                                             0, 0, 0);
            }
            __builtin_amdgcn_s_setprio(0);
            // issue next st's textS loads; latency hides under exp VALU
            if (st < 7) {
#pragma unroll
                for (int cc = 0; cc < 6; ++cc)
                    bfc[cc] = *reinterpret_cast<const bfrag8*>(
                        tSw + ((st + 1) * 6 + cc) * 512);
            }
            // scale+mask+exp2 (masked scores exp2(0)=1 participate, as ref)
#pragma unroll
            for (int r = 0; r < 4; ++r) {
                float e = exp2f((av[r] * cfr[r] + ybk[r]) * tm2r[st]);
                av[r] = e;
                lrow[r] += e;
            }
            accv[st] = av;
        }

        // block-wide denominator over S=1024
#pragma unroll
        for (int d = 1; d < 16; d <<= 1)
#pragma unroll
            for (int r = 0; r < 4; ++r) lrow[r] += __shfl_xor(lrow[r], d);
        if (l15 == 0) {
#pragma unroll
            for (int r = 0; r < 4; ++r) lred[k & 1][lg * 4 + r][w] = lrow[r];
        }
        __syncthreads();  // lred visible; all waves past af_s reads
        float rl[4];
#pragma unroll
        for (int r = 0; r < 4; ++r) {
            const float4 v0 =
                *reinterpret_cast<const float4*>(&lred[k & 1][lg * 4 + r][0]);
            const float4 v1 =
                *reinterpret_cast<const float4*>(&lred[k & 1][lg * 4 + r][4]);
            rl[r] = 1.0f /
                    (v0.x + v0.y + v0.z + v0.w + v1.x + v1.y + v1.z + v1.w);
        }
#pragma unroll
        for (int st = 0; st < 8; ++st)
#pragma unroll
            for (int r = 0; r < 4; ++r) accsum[st][r] += accv[st][r] * rl[r];
        // af_s overwrite at k+1 is safe: the lred barrier above put every
        // wave past its st-loop (af_s reads); stage happens after it.
    }

    // dump prob-sums into lds_raw (wave-private region; af_s no longer live:
    // last lred barrier ordered all af_s reads before this point)
#pragma unroll
    for (int st = 0; st < 8; ++st)
        *reinterpret_cast<f32x4*>(&lds_acc[w][st][l][0]) = accsum[st];
    __builtin_amdgcn_s_waitcnt(0);  // own-wave ds_writes visible

    // ---------------- context phase ----------------
    const short* tC = reinterpret_cast<const short*>(textC);
    f32x4 cacc[12];
#pragma unroll
    for (int c = 0; c < 12; ++c) cacc[c] = zero4;

#pragma unroll
    for (int sc = 0; sc < 4; ++sc) {
        const int scg = w * 4 + sc;
        union {
            bfrag8 v8;
            unsigned u[4];
        } A;
#pragma unroll
        for (int jp = 0; jp < 4; ++jp) {
            const int s0 = scg * 32 + lg * 8 + jp * 2;
            const int reg0 = s0 >> 7, st0 = (s0 >> 4) & 7;
            const int lo0 = (s0 & 15) | ((l15 >> 2) << 4);
            const int s1 = s0 + 1;
            const int lo1 = (s1 & 15) | ((l15 >> 2) << 4);
            const int ro = l15 & 3;
            float a = lds_acc[reg0][st0][lo0][ro];
            float bb2 = lds_acc[s1 >> 7][(s1 >> 4) & 7][lo1][ro];
            A.u[jp] = pk2(a, bb2);
        }
#pragma unroll
        for (int ctt = 0; ctt < 12; ++ctt) {
            bfrag8 bf = *reinterpret_cast<const bfrag8*>(
                tC + (((size_t)b * 12 + ctt) * 32 + scg) * 512 + (size_t)l * 8);
            cacc[ctt] = __builtin_amdgcn_mfma_f32_16x16x32_bf16(
                A.v8, bf, cacc[ctt], 0, 0, 0);
        }
    }
    __syncthreads();  // all lds_acc reads done before overwrite as 'part'

    if (w < 4) {
#pragma unroll
        for (int ctt = 0; ctt < 12; ++ctt)
#pragma unroll
            for (int r = 0; r < 4; ++r)
                part[w][lg * 4 + r][ctt * 16 + l15] = cacc[ctt][r];
    }
    __syncthreads();
    if (w >= 4) {
#pragma unroll
        for (int ctt = 0; ctt < 12; ++ctt)
#pragma unroll
            for (int r = 0; r < 4; ++r)
                part[w - 4][lg * 4 + r][ctt * 16 + l15] += cacc[ctt][r];
    }
    __syncthreads();

    // epilogue: out[b,c,t0..t0+15] = y + ctx[t][c%192] + ge[b,c]
    const float* yb_ = y + (size_t)b * CC * TT;
    float* ob = out + (size_t)b * CC * TT;
    const float* geb = ge + b * CC;
    for (int c = tid; c < CC; c += 512) {
        const float gev = geb[c];
        const int cm = c % CT;
        const float4* ysrc =
            reinterpret_cast<const float4*>(yb_ + (size_t)c * TT + t0);
        float4* od = reinterpret_cast<float4*>(ob + (size_t)c * TT + t0);
#pragma unroll
        for (int i4 = 0; i4 < 4; ++i4) {
            float4 v = ysrc[i4];
            const int row = i4 * 4;
            v.x += part[0][row + 0][cm] + part[1][row + 0][cm] +
                   part[2][row + 0][cm] + part[3][row + 0][cm] + gev;
            v.y += part[0][row + 1][cm] + part[1][row + 1][cm] +
                   part[2][row + 1][cm] + part[3][row + 1][cm] + gev;
            v.z += part[0][row + 2][cm] + part[1][row + 2][cm] +
                   part[2][row + 2][cm] + part[3][row + 2][cm] + gev;
            v.w += part[0][row + 3][cm] + part[1][row + 3][cm] +
                   part[2][row + 3][cm] + part[3][row + 3][cm] + gev;
            od[i4] = v;
        }
    }
}

// ---------------------------------------------------------------------------
extern "C" void kernel_launch(void* const* d_in, const int* in_sizes, int n_in,
                              void* d_out, int out_size, void* d_ws,
                              size_t ws_size, hipStream_t stream) {
    const float* y      = (const float*)d_in[0];
    const float* ymask  = (const float*)d_in[1];
    const float* text   = (const float*)d_in[2];
    const float* tmask  = (const float*)d_in[3];
    const float* ge     = (const float*)d_in[4];
    const float* W      = (const float*)d_in[5];
    const float* bias   = (const float*)d_in[6];
    const float* scale  = (const float*)d_in[7];
    float* out = (float*)d_out;

    // workspace carve-up (bytes)
    char* ws = (char*)d_ws;
    __hip_bfloat16* ywA   = (__hip_bfloat16*)ws;                 // 37,748,736
    float*          ybws  = (float*)(ws + 37748736);             //    393,216
    __hip_bfloat16* textS = (__hip_bfloat16*)(ws + 38141952);    //  1,572,864
    __hip_bfloat16* textC = (__hip_bfloat16*)(ws + 39714816);    //  1,572,864
    __hip_bfloat16* yP    = (__hip_bfloat16*)(ws + 58064896);    // 12,582,912
    __hip_bfloat16* WP    = (__hip_bfloat16*)(ws + 70647808);    //  3,538,944

    k_pack_all<<<512, 256, 0, stream>>>(text, W, y, bias, textS, textC, WP,
                                        yP, ybws);
    k_yw_mfma<<<1536, 256, 0, stream>>>(yP, WP, ywA);
    k_attn_fused<<<512, 512, 0, stream>>>(ymask, tmask, scale, ywA, ybws,
                                          textS, textC, y, ge, out);
}

// Round 14
// 238.219 us; speedup vs baseline: 1.0403x; 1.0403x over previous
//
#include <hip/hip_runtime.h>
#include <hip/hip_bf16.h>

// Problem constants
#define BB 4
#define CC 768
#define CT 192
#define TT 2048
#define SS 1024
#define KK 12

typedef __attribute__((ext_vector_type(8))) short bfrag8;  // 8 bf16 = 4 VGPR
typedef __attribute__((ext_vector_type(4))) float f32x4;

// ---------------------------------------------------------------------------
// Fragment-layout convention (16x16x32 bf16 MFMA):
//   A: row m = lane&15, k-slot = 32*cc + (lane>>4)*8 + j
//   B: col n = lane&15, k-slot = 32*cc + (lane>>4)*8 + j
//   D: col n = lane&15, row m = (lane>>4)*4 + reg   (HW-verified)
//
// HARD CONSTRAINTS (measured R7-R13):
//  - arch-VGPR budget pinned at 128; live sets must stay <=~120.
//  - occupancy pinned at 2 waves/SIMD by the UNIFIED VGPR+AGPR file
//    (R13: 67KB LDS still showed 22% -> LDS is NOT the cap). Latency must
//    be hidden in-wave; head-pairing's 2x textS reuse is worth its LDS.
// R14 = R12 attn (proven 135us) + af_s kp-parity double-buffer (1 barrier
// per head-pair instead of 2) + R13's merged pack / double-buffered yw.
// ---------------------------------------------------------------------------

__device__ inline unsigned pk2(float a, float b) {
    __hip_bfloat162 h2;
    h2.x = __float2bfloat16(a);
    h2.y = __float2bfloat16(b);
    return *reinterpret_cast<unsigned*>(&h2);
}
__device__ inline float unpk_lo(unsigned u) { return __uint_as_float(u << 16); }
__device__ inline float unpk_hi(unsigned u) {
    return __uint_as_float(u & 0xffff0000u);
}

// ---------------------------------------------------------------------------
// ONE pack kernel, 512 blocks (R13, proven):
//   blk 0..31   : textS/textC   blk 32..127 : WP
//   blk 128..255: yP via LDS transpose   blk 256..511: yb (bias dot)
// ---------------------------------------------------------------------------
__global__ __launch_bounds__(256) void k_pack_all(
    const float* __restrict__ text, const float* __restrict__ W,
    const float* __restrict__ y, const float* __restrict__ bias,
    __hip_bfloat16* __restrict__ textS, __hip_bfloat16* __restrict__ textC,
    __hip_bfloat16* __restrict__ WP, __hip_bfloat16* __restrict__ yP,
    float* __restrict__ ybws) {
    __shared__ __align__(16) char pk_lds[49152];  // union
    const int blk = blockIdx.x;
    const int tid = threadIdx.x;

    if (blk < 32) {
        const int b = blk >> 3;
        const float* tb = text + (size_t)b * CT * SS;
        const int base = tid + (blk & 7) * 256;
        for (int e = base; e < 64 * 6 * 512; e += 2048) {
            int jj = e & 7, l = (e >> 3) & 63, cc = (e >> 9) % 6, st = e / 3072;
            int ct = cc * 32 + ((l >> 4) << 3) + jj;
            int s = st * 16 + (l & 15);
            textS[(size_t)b * 196608 + e] =
                __float2bfloat16(tb[(size_t)ct * SS + s]);
        }
        for (int e = base; e < 12 * 32 * 512; e += 2048) {
            int jj = e & 7, l = (e >> 3) & 63, scg = (e >> 9) & 31,
                ctt = e / 16384;
            int ct = ctt * 16 + (l & 15);
            int s = scg * 32 + ((l >> 4) << 3) + jj;
            textC[(size_t)b * 196608 + e] =
                __float2bfloat16(tb[(size_t)ct * SS + s]);
        }
    } else if (blk < 128) {
        const int k = (blk - 32) >> 3;
        const float* wk = W + (size_t)k * CC * CT;
        const int base = tid + ((blk - 32) & 7) * 256;
        for (int e = base; e < 12 * 24 * 512; e += 2048) {
            int j = e & 7, l = (e >> 3) & 63, oc = (e >> 9) % 24, nt = e / 12288;
            int ct = nt * 16 + (l & 15);
            int o = oc * 32 + ((l >> 4) << 3) + j;
            WP[(size_t)k * 147456 + e] =
                __float2bfloat16(wk[(size_t)o * CT + ct]);
        }
    } else if (blk < 256) {
        float(*tile)[64] = reinterpret_cast<float(*)[64]>(pk_lds);  // 8K
        const int idx = blk - 128;
        const int b = idx >> 5;
        const int tq = idx & 31;
        const int t0 = tq * 64;
        const float* yb_ = y + (size_t)b * CC * TT;
        const int w = tid >> 6, l = tid & 63;
        const int l15 = l & 15, lg = l >> 4;
        const int row0 = tid >> 4;
        const int c4 = tid & 15;

        for (int oc = 0; oc < 24; ++oc) {
#pragma unroll
            for (int h = 0; h < 2; ++h) {
                const int row = row0 + h * 16;
                const float4 v = *reinterpret_cast<const float4*>(
                    yb_ + (size_t)(oc * 32 + row) * TT + t0 + c4 * 4);
                *reinterpret_cast<float4*>(&tile[row][c4 * 4]) = v;
            }
            __syncthreads();
            union {
                bfrag8 v8;
                short u[8];
            } A;
#pragma unroll
            for (int j = 0; j < 8; ++j)
                A.u[j] = (short)__bfloat16_as_ushort(
                    __float2bfloat16(tile[lg * 8 + j][w * 16 + l15]));
            __hip_bfloat16* dst =
                yP + (((size_t)(b * 128 + tq * 4 + w) * 24 + oc) * 512) +
                (size_t)l * 8;
            *reinterpret_cast<bfrag8*>(dst) = A.v8;
            __syncthreads();
        }
    } else {
        float(*bs)[CC] = reinterpret_cast<float(*)[CC]>(pk_lds);  // 36K
        float(*pb)[32][KK] =
            reinterpret_cast<float(*)[32][KK]>(pk_lds + 36864);   // 12K
        const int idx = blk - 256;
        const int b = idx >> 6;
        const int t0 = (idx & 63) * 32;
        const int tl = tid & 31, g = tid >> 5;  // 8 groups x 96 o

        for (int i = tid; i < KK * CC; i += 256) bs[i / CC][i % CC] = bias[i];
        __syncthreads();

        float p[KK];
#pragma unroll
        for (int k = 0; k < KK; ++k) p[k] = 0.f;
        const float* yb_ = y + (size_t)b * CC * TT + t0 + tl;
        for (int o = g * 96; o < g * 96 + 96; ++o) {
            float v = yb_[(size_t)o * TT];
#pragma unroll
            for (int k = 0; k < KK; ++k) p[k] += v * bs[k][o];
        }
#pragma unroll
        for (int k = 0; k < KK; ++k) pb[g][tl][k] = p[k];
        __syncthreads();
        for (int i = tid; i < 32 * KK; i += 256) {
            int t = i / KK, k = i % KK;
            float s = 0.f;
#pragma unroll
            for (int gg = 0; gg < 8; ++gg) s += pb[gg][t][k];
            ybws[((size_t)k * BB + b) * TT + t0 + t] = s;
        }
    }
}

// ---------------------------------------------------------------------------
// yW via MFMA (R13, proven). 1536 blocks, XCD b-affinity swizzle,
// wave = 3 nt x 4 ttg, 2-deep af/bf double-buffer, padded-LDS epilogue.
// ---------------------------------------------------------------------------
__global__ __launch_bounds__(256, 2) void k_yw_mfma(
    const __hip_bfloat16* __restrict__ yP, const __hip_bfloat16* __restrict__ WP,
    __hip_bfloat16* __restrict__ ywA) {
    const int i = blockIdx.x;
    const int x = i & 7, j = i >> 3;
    const int b = x & 3;
    const int k = j >> 4;
    const int tx = (j & 15) | ((x >> 2) << 4);
    const int kb = k * BB + b;

    const int tid = threadIdx.x;
    const int w = tid >> 6, l = tid & 63;
    const int l15 = l & 15, lg = l >> 4;
    const int ttg0 = tx * 4;
    const int nt0 = 3 * w;

    __shared__ float ot[4][16][197];  // 50.4 KB

    const short* ypb = reinterpret_cast<const short*>(yP) +
                       (((size_t)b * 128 + ttg0) * 24) * 512 + (size_t)l * 8;
    const short* wp = reinterpret_cast<const short*>(WP) +
                      (size_t)k * 147456 + (size_t)l * 8;

    f32x4 acc[3][4];
#pragma unroll
    for (int n = 0; n < 3; ++n)
#pragma unroll
        for (int tg = 0; tg < 4; ++tg) acc[n][tg] = (f32x4){0.f, 0.f, 0.f, 0.f};

    bfrag8 af[2][4], bf[2][3];
#pragma unroll
    for (int tg = 0; tg < 4; ++tg)
        af[0][tg] = *reinterpret_cast<const bfrag8*>(ypb + (tg * 24) * 512);
#pragma unroll
    for (int n = 0; n < 3; ++n)
        bf[0][n] = *reinterpret_cast<const bfrag8*>(wp + ((nt0 + n) * 24) * 512);

#pragma unroll
    for (int oc = 0; oc < 24; ++oc) {
        const int cur = oc & 1, nxt = cur ^ 1;
        if (oc < 23) {
#pragma unroll
            for (int tg = 0; tg < 4; ++tg)
                af[nxt][tg] = *reinterpret_cast<const bfrag8*>(
                    ypb + (tg * 24 + oc + 1) * 512);
#pragma unroll
            for (int n = 0; n < 3; ++n)
                bf[nxt][n] = *reinterpret_cast<const bfrag8*>(
                    wp + ((nt0 + n) * 24 + oc + 1) * 512);
        }
#pragma unroll
        for (int n = 0; n < 3; ++n)
#pragma unroll
            for (int tg = 0; tg < 4; ++tg)
                acc[n][tg] = __builtin_amdgcn_mfma_f32_16x16x32_bf16(
                    af[cur][tg], bf[cur][n], acc[n][tg], 0, 0, 0);
    }

#pragma unroll
    for (int n = 0; n < 3; ++n) {
        const int ct = (w * 3 + n) * 16 + l15;
#pragma unroll
        for (int tg = 0; tg < 4; ++tg)
#pragma unroll
            for (int r = 0; r < 4; ++r) ot[tg][lg * 4 + r][ct] = acc[n][tg][r];
    }
    __syncthreads();

    const size_t obase = ((size_t)kb * 128 + ttg0 + w) * 3072;
#pragma unroll
    for (int cc = 0; cc < 6; ++cc) {
        union {
            bfrag8 v8;
            short u[8];
        } A;
#pragma unroll
        for (int j2 = 0; j2 < 8; ++j2)
            A.u[j2] = (short)__bfloat16_as_ushort(
                __float2bfloat16(ot[w][l15][cc * 32 + lg * 8 + j2]));
        *reinterpret_cast<bfrag8*>(
            reinterpret_cast<short*>(ywA) + obase + cc * 512 + (size_t)l * 8) =
            A.v8;
    }
}

// ---------------------------------------------------------------------------
// FUSED attn = R12 (head-paired, exp_buf, af_s shared via LDS, bfc textS
// prefetch, exp2 — proven 135us / FETCH 41.7MB / no spill) with af_s now
// DOUBLE-BUFFERED by kp-parity: kp+1's A-frags are staged right after the
// st-loop, and the single lred barrier orders both lred reads and the next
// stage -> 1 barrier per head-pair (was 2).
// Safety: stage writes target af_s[nxt] while st-loops read af_s[cur];
// exp_buf/lds_acc RMW after the barrier are wave-private; lred[kp&1] reuse
// is separated by the kp+1 barrier.
// ---------------------------------------------------------------------------
__global__ __launch_bounds__(512) void k_attn_fused(
    const float* __restrict__ ymask, const float* __restrict__ tmask,
    const float* __restrict__ scale, const __hip_bfloat16* __restrict__ ywA,
    const float* __restrict__ ybws, const __hip_bfloat16* __restrict__ textS,
    const __hip_bfloat16* __restrict__ textC, const float* __restrict__ y,
    const float* __restrict__ ge, float* __restrict__ out) {
    const int i = blockIdx.x;
    const int x = i & 7;
    const int b = x & 3;
    const int tt = (i >> 3) + ((x >> 2) << 6);
    const int t0 = tt * 16;
    const int tid = threadIdx.x;
    const int w = tid >> 6;       // 0..7
    const int l = tid & 63;
    const int l15 = l & 15, lg = l >> 4;
    const int ws0 = w * 128;

    __shared__ float lds_acc[8][8][64][4];             // 64 KB: prob-sum acc
    __shared__ uint2 exp_buf[2][8][8][64];             // 64 KB: bf16 exp x4
    __shared__ __align__(16) short af_s[2][2][6][64][8];  // 24 KB dbuf A-frags
    __shared__ float yb_s[KK][16];
    __shared__ float sc_s[KK];
    __shared__ __align__(16) float lred[2][2][16][8];  // [kp&1][p][row][w]

    if (tid < 192)
        yb_s[tid >> 4][tid & 15] =
            ybws[(size_t)((tid >> 4) * BB + b) * TT + t0 + (tid & 15)];
    if (tid < KK) sc_s[tid] = scale[tid];
    const f32x4 zero4 = (f32x4){0.f, 0.f, 0.f, 0.f};
#pragma unroll
    for (int st = 0; st < 8; ++st)
        *reinterpret_cast<f32x4*>(&lds_acc[w][st][l][0]) = zero4;

    float tm2r[8];
#pragma unroll
    for (int st = 0; st < 8; ++st) {
        float m = tmask[b * SS + ws0 + st * 16 + l15];
        tm2r[st] = m * m;
    }
    float ymr[4];
#pragma unroll
    for (int r = 0; r < 4; ++r) ymr[r] = ymask[b * TT + t0 + lg * 4 + r];
    // 1/sqrt(768) * log2(e); exp(x) computed as exp2(x*log2e)
    const float invs_l2e = 0.03608439182435161f * 1.4426950408889634f;

    const short* ywAs = reinterpret_cast<const short*>(ywA);
    const short* tS = reinterpret_cast<const short*>(textS);
    const short* tSw = tS + (((size_t)b * 64 + w * 8) * 6) * 512 + (size_t)l * 8;
    const size_t headStride = (size_t)BB * 128 * 3072;  // shorts per head

    // prologue: stage kp=0's head-pair A-frags into buffer 0
    {
        const size_t ab0_l0 = (((size_t)(0 * BB + b) * 128 + tt) * 6) * 512;
        for (int u = tid; u < 768; u += 512) {
            const int p = u / 384;
            const int rem = u - p * 384;
            const int cc2 = rem >> 6;
            const int l2 = rem & 63;
            bfrag8 v = *reinterpret_cast<const bfrag8*>(
                ywAs + ab0_l0 + (size_t)p * headStride + cc2 * 512 + l2 * 8);
            *reinterpret_cast<bfrag8*>(&af_s[0][p][cc2][l2][0]) = v;
        }
    }
    __syncthreads();  // af_s[0] + lds_acc zero + yb_s/sc_s ready

    for (int kp = 0; kp < 6; ++kp) {
        const int cb = kp & 1;
        float cfr[2][4], ybk[2][4];
#pragma unroll
        for (int p = 0; p < 2; ++p) {
            const int k = 2 * kp + p;
            const float sk = sc_s[k] * invs_l2e;
#pragma unroll
            for (int r = 0; r < 4; ++r) {
                const float cf = sk * ymr[r];
                cfr[p][r] = cf;
                ybk[p][r] = yb_s[k][lg * 4 + r] * cf;  // pre-scaled bias
            }
        }

        // prime the textS pipeline: st=0's B-frags
        bfrag8 bfc[6];
#pragma unroll
        for (int cc = 0; cc < 6; ++cc)
            bfc[cc] = *reinterpret_cast<const bfrag8*>(tSw + cc * 512);

        float lrow[2][4] = {{0.f, 0.f, 0.f, 0.f}, {0.f, 0.f, 0.f, 0.f}};
#pragma unroll
        for (int st = 0; st < 8; ++st) {
            f32x4 av0 = zero4, av1 = zero4;
            __builtin_amdgcn_s_setprio(1);
#pragma unroll
            for (int cc = 0; cc < 6; ++cc) {
                bfrag8 a0 =
                    *reinterpret_cast<const bfrag8*>(&af_s[cb][0][cc][l][0]);
                bfrag8 a1 =
                    *reinterpret_cast<const bfrag8*>(&af_s[cb][1][cc][l][0]);
                av0 = __builtin_amdgcn_mfma_f32_16x16x32_bf16(a0, bfc[cc],
                                                              av0, 0, 0, 0);
                av1 = __builtin_amdgcn_mfma_f32_16x16x32_bf16(a1, bfc[cc],
                                                              av1, 0, 0, 0);
            }
            __builtin_amdgcn_s_setprio(0);
            // issue next st's textS loads; latency hides under exp VALU
            if (st < 7) {
#pragma unroll
                for (int cc = 0; cc < 6; ++cc)
                    bfc[cc] = *reinterpret_cast<const bfrag8*>(
                        tSw + ((st + 1) * 6 + cc) * 512);
            }
            // scale+mask+exp2 (masked scores exp2(0)=1 participate, as ref)
#pragma unroll
            for (int r = 0; r < 4; ++r) {
                float e0 = exp2f((av0[r] * cfr[0][r] + ybk[0][r]) * tm2r[st]);
                float e1 = exp2f((av1[r] * cfr[1][r] + ybk[1][r]) * tm2r[st]);
                av0[r] = e0;
                av1[r] = e1;
                lrow[0][r] += e0;
                lrow[1][r] += e1;
            }
            exp_buf[0][w][st][l] =
                make_uint2(pk2(av0[0], av0[1]), pk2(av0[2], av0[3]));
            exp_buf[1][w][st][l] =
                make_uint2(pk2(av1[0], av1[1]), pk2(av1[2], av1[3]));
        }

        // stage NEXT head-pair's A-frags into the other buffer (no barrier:
        // concurrent st-loops read af_s[cb], we write af_s[cb^1])
        if (kp < 5) {
            const size_t abn =
                (((size_t)(2 * (kp + 1) * BB + b) * 128 + tt) * 6) * 512;
            for (int u = tid; u < 768; u += 512) {
                const int p = u / 384;
                const int rem = u - p * 384;
                const int cc2 = rem >> 6;
                const int l2 = rem & 63;
                bfrag8 v = *reinterpret_cast<const bfrag8*>(
                    ywAs + abn + (size_t)p * headStride + cc2 * 512 + l2 * 8);
                *reinterpret_cast<bfrag8*>(&af_s[cb ^ 1][p][cc2][l2][0]) = v;
            }
        }

        // block-wide denominator over S=1024
#pragma unroll
        for (int d = 1; d < 16; d <<= 1)
#pragma unroll
            for (int p = 0; p < 2; ++p)
#pragma unroll
                for (int r = 0; r < 4; ++r)
                    lrow[p][r] += __shfl_xor(lrow[p][r], d);
        if (l15 == 0) {
#pragma unroll
            for (int p = 0; p < 2; ++p)
#pragma unroll
                for (int r = 0; r < 4; ++r)
                    lred[cb][p][lg * 4 + r][w] = lrow[p][r];
        }
        __syncthreads();  // orders: lred visible, af_s[cb^1] staged, all
                          // waves past af_s[cb] reads
        float rl[2][4];
#pragma unroll
        for (int p = 0; p < 2; ++p)
#pragma unroll
            for (int r = 0; r < 4; ++r) {
                const float4 v0 = *reinterpret_cast<const float4*>(
                    &lred[cb][p][lg * 4 + r][0]);
                const float4 v1 = *reinterpret_cast<const float4*>(
                    &lred[cb][p][lg * 4 + r][4]);
                rl[p][r] = 1.0f / (v0.x + v0.y + v0.z + v0.w + v1.x + v1.y +
                                   v1.z + v1.w);
            }
        // read exp back, normalize, accumulate (all LDS, wave-private)
#pragma unroll
        for (int st = 0; st < 8; ++st) {
            const uint2 e0 = exp_buf[0][w][st][l];
            const uint2 e1 = exp_buf[1][w][st][l];
            f32x4 cur = *reinterpret_cast<f32x4*>(&lds_acc[w][st][l][0]);
            cur[0] += unpk_lo(e0.x) * rl[0][0] + unpk_lo(e1.x) * rl[1][0];
            cur[1] += unpk_hi(e0.x) * rl[0][1] + unpk_hi(e1.x) * rl[1][1];
            cur[2] += unpk_lo(e0.y) * rl[0][2] + unpk_lo(e1.y) * rl[1][2];
            cur[3] += unpk_hi(e0.y) * rl[0][3] + unpk_hi(e1.y) * rl[1][3];
            *reinterpret_cast<f32x4*>(&lds_acc[w][st][l][0]) = cur;
        }
        // lred[cb] reuse at kp+2 is ordered by the barrier at kp+1.
    }
    __builtin_amdgcn_s_waitcnt(0);  // own-wave lds_acc writes visible

    // ---------------- context phase ----------------
    const short* tC = reinterpret_cast<const short*>(textC);
    f32x4 cacc[12];
#pragma unroll
    for (int c = 0; c < 12; ++c) cacc[c] = (f32x4){0.f, 0.f, 0.f, 0.f};

#pragma unroll
    for (int sc = 0; sc < 4; ++sc) {
        const int scg = w * 4 + sc;
        union {
            bfrag8 v8;
            unsigned u[4];
        } A;
#pragma unroll
        for (int jp = 0; jp < 4; ++jp) {
            const int s0 = scg * 32 + lg * 8 + jp * 2;
            const int reg0 = s0 >> 7, st0 = (s0 >> 4) & 7;
            const int lo0 = (s0 & 15) | ((l15 >> 2) << 4);
            const int s1 = s0 + 1;
            const int lo1 = (s1 & 15) | ((l15 >> 2) << 4);
            const int ro = l15 & 3;
            float a = lds_acc[reg0][st0][lo0][ro];
            float bb2 = lds_acc[s1 >> 7][(s1 >> 4) & 7][lo1][ro];
            A.u[jp] = pk2(a, bb2);
        }
#pragma unroll
        for (int ctt = 0; ctt < 12; ++ctt) {
            bfrag8 bf = *reinterpret_cast<const bfrag8*>(
                tC + (((size_t)b * 12 + ctt) * 32 + scg) * 512 + (size_t)l * 8);
            cacc[ctt] = __builtin_amdgcn_mfma_f32_16x16x32_bf16(
                A.v8, bf, cacc[ctt], 0, 0, 0);
        }
    }
    __syncthreads();  // all lds_acc reads done before overwrite as 'part'

    float(*part)[16][192] =
        reinterpret_cast<float(*)[16][192]>(&lds_acc[0][0][0][0]);
    if (w < 4) {
#pragma unroll
        for (int ctt = 0; ctt < 12; ++ctt)
#pragma unroll
            for (int r = 0; r < 4; ++r)
                part[w][lg * 4 + r][ctt * 16 + l15] = cacc[ctt][r];
    }
    __syncthreads();
    if (w >= 4) {
#pragma unroll
        for (int ctt = 0; ctt < 12; ++ctt)
#pragma unroll
            for (int r = 0; r < 4; ++r)
                part[w - 4][lg * 4 + r][ctt * 16 + l15] += cacc[ctt][r];
    }
    __syncthreads();

    // epilogue: out[b,c,t0..t0+15] = y + ctx[t][c%192] + ge[b,c]
    const float* yb_ = y + (size_t)b * CC * TT;
    float* ob = out + (size_t)b * CC * TT;
    const float* geb = ge + b * CC;
    for (int c = tid; c < CC; c += 512) {
        const float gev = geb[c];
        const int cm = c % CT;
        const float4* ysrc =
            reinterpret_cast<const float4*>(yb_ + (size_t)c * TT + t0);
        float4* od = reinterpret_cast<float4*>(ob + (size_t)c * TT + t0);
#pragma unroll
        for (int i4 = 0; i4 < 4; ++i4) {
            float4 v = ysrc[i4];
            const int row = i4 * 4;
            v.x += part[0][row + 0][cm] + part[1][row + 0][cm] +
                   part[2][row + 0][cm] + part[3][row + 0][cm] + gev;
            v.y += part[0][row + 1][cm] + part[1][row + 1][cm] +
                   part[2][row + 1][cm] + part[3][row + 1][cm] + gev;
            v.z += part[0][row + 2][cm] + part[1][row + 2][cm] +
                   part[2][row + 2][cm] + part[3][row + 2][cm] + gev;
            v.w += part[0][row + 3][cm] + part[1][row + 3][cm] +
                   part[2][row + 3][cm] + part[3][row + 3][cm] + gev;
            od[i4] = v;
        }
    }
}

// ---------------------------------------------------------------------------
extern "C" void kernel_launch(void* const* d_in, const int* in_sizes, int n_in,
                              void* d_out, int out_size, void* d_ws,
                              size_t ws_size, hipStream_t stream) {
    const float* y      = (const float*)d_in[0];
    const float* ymask  = (const float*)d_in[1];
    const float* text   = (const float*)d_in[2];
    const float* tmask  = (const float*)d_in[3];
    const float* ge     = (const float*)d_in[4];
    const float* W      = (const float*)d_in[5];
    const float* bias   = (const float*)d_in[6];
    const float* scale  = (const float*)d_in[7];
    float* out = (float*)d_out;

    // workspace carve-up (bytes)
    char* ws = (char*)d_ws;
    __hip_bfloat16* ywA   = (__hip_bfloat16*)ws;                 // 37,748,736
    float*          ybws  = (float*)(ws + 37748736);             //    393,216
    __hip_bfloat16* textS = (__hip_bfloat16*)(ws + 38141952);    //  1,572,864
    __hip_bfloat16* textC = (__hip_bfloat16*)(ws + 39714816);    //  1,572,864
    __hip_bfloat16* yP    = (__hip_bfloat16*)(ws + 58064896);    // 12,582,912
    __hip_bfloat16* WP    = (__hip_bfloat16*)(ws + 70647808);    //  3,538,944

    k_pack_all<<<512, 256, 0, stream>>>(text, W, y, bias, textS, textC, WP,
                                        yP, ybws);
    k_yw_mfma<<<1536, 256, 0, stream>>>(yP, WP, ywA);
    k_attn_fused<<<512, 512, 0, stream>>>(ymask, tmask, scale, ywA, ybws,
                                          textS, textC, y, ge, out);
}

// Round 15
// 201.396 us; speedup vs baseline: 1.2305x; 1.1828x over previous
//
#include <hip/hip_runtime.h>
#include <hip/hip_bf16.h>

// Problem constants
#define BB 4
#define CC 768
#define CT 192
#define TT 2048
#define SS 1024
#define KK 12

typedef __attribute__((ext_vector_type(8))) short bfrag8;  // 8 bf16 = 4 VGPR
typedef __attribute__((ext_vector_type(4))) float f32x4;

// ---------------------------------------------------------------------------
// Fragment-layout convention (16x16x32 bf16 MFMA):
//   A: row m = lane&15, k-slot = 32*cc + (lane>>4)*8 + j
//   B: col n = lane&15, k-slot = 32*cc + (lane>>4)*8 + j
//   D: col n = lane&15, row m = (lane>>4)*4 + reg   (HW-verified)
//
// HARD CONSTRAINTS (measured R7-R14):
//  - arch-VGPR budget pinned at 128; live sets must stay <=~120. ANY code
//    motion extending live ranges across the st-loop spills (R11, R14).
//  - occupancy pinned at 2 waves/SIMD by the unified VGPR+AGPR file
//    (R13: 67KB LDS still 22%); latency hidden in-wave only.
// R15 = pure recombination of proven halves:
//   attn  = Round-12-benched kernel verbatim (135us, FETCH 41.7MB, no spill)
//   pre   = R13 pack_all (yb merged) + R13 yw_mfma (2-deep dbuf) (68us)
// ---------------------------------------------------------------------------

__device__ inline unsigned pk2(float a, float b) {
    __hip_bfloat162 h2;
    h2.x = __float2bfloat16(a);
    h2.y = __float2bfloat16(b);
    return *reinterpret_cast<unsigned*>(&h2);
}
__device__ inline float unpk_lo(unsigned u) { return __uint_as_float(u << 16); }
__device__ inline float unpk_hi(unsigned u) {
    return __uint_as_float(u & 0xffff0000u);
}

// ---------------------------------------------------------------------------
// ONE pack kernel, 512 blocks (R13, proven):
//   blk 0..31   : textS/textC   blk 32..127 : WP
//   blk 128..255: yP via LDS transpose   blk 256..511: yb (bias dot)
// ---------------------------------------------------------------------------
__global__ __launch_bounds__(256) void k_pack_all(
    const float* __restrict__ text, const float* __restrict__ W,
    const float* __restrict__ y, const float* __restrict__ bias,
    __hip_bfloat16* __restrict__ textS, __hip_bfloat16* __restrict__ textC,
    __hip_bfloat16* __restrict__ WP, __hip_bfloat16* __restrict__ yP,
    float* __restrict__ ybws) {
    __shared__ __align__(16) char pk_lds[49152];  // union
    const int blk = blockIdx.x;
    const int tid = threadIdx.x;

    if (blk < 32) {
        const int b = blk >> 3;
        const float* tb = text + (size_t)b * CT * SS;
        const int base = tid + (blk & 7) * 256;
        for (int e = base; e < 64 * 6 * 512; e += 2048) {
            int jj = e & 7, l = (e >> 3) & 63, cc = (e >> 9) % 6, st = e / 3072;
            int ct = cc * 32 + ((l >> 4) << 3) + jj;
            int s = st * 16 + (l & 15);
            textS[(size_t)b * 196608 + e] =
                __float2bfloat16(tb[(size_t)ct * SS + s]);
        }
        for (int e = base; e < 12 * 32 * 512; e += 2048) {
            int jj = e & 7, l = (e >> 3) & 63, scg = (e >> 9) & 31,
                ctt = e / 16384;
            int ct = ctt * 16 + (l & 15);
            int s = scg * 32 + ((l >> 4) << 3) + jj;
            textC[(size_t)b * 196608 + e] =
                __float2bfloat16(tb[(size_t)ct * SS + s]);
        }
    } else if (blk < 128) {
        const int k = (blk - 32) >> 3;
        const float* wk = W + (size_t)k * CC * CT;
        const int base = tid + ((blk - 32) & 7) * 256;
        for (int e = base; e < 12 * 24 * 512; e += 2048) {
            int j = e & 7, l = (e >> 3) & 63, oc = (e >> 9) % 24, nt = e / 12288;
            int ct = nt * 16 + (l & 15);
            int o = oc * 32 + ((l >> 4) << 3) + j;
            WP[(size_t)k * 147456 + e] =
                __float2bfloat16(wk[(size_t)o * CT + ct]);
        }
    } else if (blk < 256) {
        float(*tile)[64] = reinterpret_cast<float(*)[64]>(pk_lds);  // 8K
        const int idx = blk - 128;
        const int b = idx >> 5;
        const int tq = idx & 31;
        const int t0 = tq * 64;
        const float* yb_ = y + (size_t)b * CC * TT;
        const int w = tid >> 6, l = tid & 63;
        const int l15 = l & 15, lg = l >> 4;
        const int row0 = tid >> 4;
        const int c4 = tid & 15;

        for (int oc = 0; oc < 24; ++oc) {
#pragma unroll
            for (int h = 0; h < 2; ++h) {
                const int row = row0 + h * 16;
                const float4 v = *reinterpret_cast<const float4*>(
                    yb_ + (size_t)(oc * 32 + row) * TT + t0 + c4 * 4);
                *reinterpret_cast<float4*>(&tile[row][c4 * 4]) = v;
            }
            __syncthreads();
            union {
                bfrag8 v8;
                short u[8];
            } A;
#pragma unroll
            for (int j = 0; j < 8; ++j)
                A.u[j] = (short)__bfloat16_as_ushort(
                    __float2bfloat16(tile[lg * 8 + j][w * 16 + l15]));
            __hip_bfloat16* dst =
                yP + (((size_t)(b * 128 + tq * 4 + w) * 24 + oc) * 512) +
                (size_t)l * 8;
            *reinterpret_cast<bfrag8*>(dst) = A.v8;
            __syncthreads();
        }
    } else {
        float(*bs)[CC] = reinterpret_cast<float(*)[CC]>(pk_lds);  // 36K
        float(*pb)[32][KK] =
            reinterpret_cast<float(*)[32][KK]>(pk_lds + 36864);   // 12K
        const int idx = blk - 256;
        const int b = idx >> 6;
        const int t0 = (idx & 63) * 32;
        const int tl = tid & 31, g = tid >> 5;  // 8 groups x 96 o

        for (int i = tid; i < KK * CC; i += 256) bs[i / CC][i % CC] = bias[i];
        __syncthreads();

        float p[KK];
#pragma unroll
        for (int k = 0; k < KK; ++k) p[k] = 0.f;
        const float* yb_ = y + (size_t)b * CC * TT + t0 + tl;
        for (int o = g * 96; o < g * 96 + 96; ++o) {
            float v = yb_[(size_t)o * TT];
#pragma unroll
            for (int k = 0; k < KK; ++k) p[k] += v * bs[k][o];
        }
#pragma unroll
        for (int k = 0; k < KK; ++k) pb[g][tl][k] = p[k];
        __syncthreads();
        for (int i = tid; i < 32 * KK; i += 256) {
            int t = i / KK, k = i % KK;
            float s = 0.f;
#pragma unroll
            for (int gg = 0; gg < 8; ++gg) s += pb[gg][t][k];
            ybws[((size_t)k * BB + b) * TT + t0 + t] = s;
        }
    }
}

// ---------------------------------------------------------------------------
// yW via MFMA (R13, proven). 1536 blocks, XCD b-affinity swizzle,
// wave = 3 nt x 4 ttg, 2-deep af/bf double-buffer, padded-LDS epilogue.
// ---------------------------------------------------------------------------
__global__ __launch_bounds__(256, 2) void k_yw_mfma(
    const __hip_bfloat16* __restrict__ yP, const __hip_bfloat16* __restrict__ WP,
    __hip_bfloat16* __restrict__ ywA) {
    const int i = blockIdx.x;
    const int x = i & 7, j = i >> 3;
    const int b = x & 3;
    const int k = j >> 4;
    const int tx = (j & 15) | ((x >> 2) << 4);
    const int kb = k * BB + b;

    const int tid = threadIdx.x;
    const int w = tid >> 6, l = tid & 63;
    const int l15 = l & 15, lg = l >> 4;
    const int ttg0 = tx * 4;
    const int nt0 = 3 * w;

    __shared__ float ot[4][16][197];  // 50.4 KB

    const short* ypb = reinterpret_cast<const short*>(yP) +
                       (((size_t)b * 128 + ttg0) * 24) * 512 + (size_t)l * 8;
    const short* wp = reinterpret_cast<const short*>(WP) +
                      (size_t)k * 147456 + (size_t)l * 8;

    f32x4 acc[3][4];
#pragma unroll
    for (int n = 0; n < 3; ++n)
#pragma unroll
        for (int tg = 0; tg < 4; ++tg) acc[n][tg] = (f32x4){0.f, 0.f, 0.f, 0.f};

    bfrag8 af[2][4], bf[2][3];
#pragma unroll
    for (int tg = 0; tg < 4; ++tg)
        af[0][tg] = *reinterpret_cast<const bfrag8*>(ypb + (tg * 24) * 512);
#pragma unroll
    for (int n = 0; n < 3; ++n)
        bf[0][n] = *reinterpret_cast<const bfrag8*>(wp + ((nt0 + n) * 24) * 512);

#pragma unroll
    for (int oc = 0; oc < 24; ++oc) {
        const int cur = oc & 1, nxt = cur ^ 1;
        if (oc < 23) {
#pragma unroll
            for (int tg = 0; tg < 4; ++tg)
                af[nxt][tg] = *reinterpret_cast<const bfrag8*>(
                    ypb + (tg * 24 + oc + 1) * 512);
#pragma unroll
            for (int n = 0; n < 3; ++n)
                bf[nxt][n] = *reinterpret_cast<const bfrag8*>(
                    wp + ((nt0 + n) * 24 + oc + 1) * 512);
        }
#pragma unroll
        for (int n = 0; n < 3; ++n)
#pragma unroll
            for (int tg = 0; tg < 4; ++tg)
                acc[n][tg] = __builtin_amdgcn_mfma_f32_16x16x32_bf16(
                    af[cur][tg], bf[cur][n], acc[n][tg], 0, 0, 0);
    }

#pragma unroll
    for (int n = 0; n < 3; ++n) {
        const int ct = (w * 3 + n) * 16 + l15;
#pragma unroll
        for (int tg = 0; tg < 4; ++tg)
#pragma unroll
            for (int r = 0; r < 4; ++r) ot[tg][lg * 4 + r][ct] = acc[n][tg][r];
    }
    __syncthreads();

    const size_t obase = ((size_t)kb * 128 + ttg0 + w) * 3072;
#pragma unroll
    for (int cc = 0; cc < 6; ++cc) {
        union {
            bfrag8 v8;
            short u[8];
        } A;
#pragma unroll
        for (int j2 = 0; j2 < 8; ++j2)
            A.u[j2] = (short)__bfloat16_as_ushort(
                __float2bfloat16(ot[w][l15][cc * 32 + lg * 8 + j2]));
        *reinterpret_cast<bfrag8*>(
            reinterpret_cast<short*>(ywA) + obase + cc * 512 + (size_t)l * 8) =
            A.v8;
    }
}

// ---------------------------------------------------------------------------
// FUSED attn — Round-12-benched kernel VERBATIM (135us, FETCH 41.7MB):
// head-paired scores; af_s staged in LDS once per kp (single buffer, stage
// barrier + lred barrier per kp); textS bfc prefetch; exp via exp2;
// exp values in LDS exp_buf (bf16-packed); prob-sum RMW in lds_acc;
// context MFMA from lds_acc transpose + fused epilogue.
// ---------------------------------------------------------------------------
__global__ __launch_bounds__(512) void k_attn_fused(
    const float* __restrict__ ymask, const float* __restrict__ tmask,
    const float* __restrict__ scale, const __hip_bfloat16* __restrict__ ywA,
    const float* __restrict__ ybws, const __hip_bfloat16* __restrict__ textS,
    const __hip_bfloat16* __restrict__ textC, const float* __restrict__ y,
    const float* __restrict__ ge, float* __restrict__ out) {
    const int i = blockIdx.x;
    const int x = i & 7;
    const int b = x & 3;
    const int tt = (i >> 3) + ((x >> 2) << 6);
    const int t0 = tt * 16;
    const int tid = threadIdx.x;
    const int w = tid >> 6;       // 0..7
    const int l = tid & 63;
    const int l15 = l & 15, lg = l >> 4;
    const int ws0 = w * 128;

    __shared__ float lds_acc[8][8][64][4];          // 64 KB: prob-sum acc
    __shared__ uint2 exp_buf[2][8][8][64];          // 64 KB: bf16 exp x4
    __shared__ __align__(16) short af_s[2][6][64][8];  // 24 KB: shared A-frags
    __shared__ float yb_s[KK][16];
    __shared__ float sc_s[KK];
    __shared__ __align__(16) float lred[2][2][16][8];  // [kp&1][p][row][w]

    if (tid < 192)
        yb_s[tid >> 4][tid & 15] =
            ybws[(size_t)((tid >> 4) * BB + b) * TT + t0 + (tid & 15)];
    if (tid < KK) sc_s[tid] = scale[tid];
    const f32x4 zero4 = (f32x4){0.f, 0.f, 0.f, 0.f};
#pragma unroll
    for (int st = 0; st < 8; ++st)
        *reinterpret_cast<f32x4*>(&lds_acc[w][st][l][0]) = zero4;

    float tm2r[8];
#pragma unroll
    for (int st = 0; st < 8; ++st) {
        float m = tmask[b * SS + ws0 + st * 16 + l15];
        tm2r[st] = m * m;
    }
    float ymr[4];
#pragma unroll
    for (int r = 0; r < 4; ++r) ymr[r] = ymask[b * TT + t0 + lg * 4 + r];
    // 1/sqrt(768) * log2(e); exp(x) computed as exp2(x*log2e)
    const float invs_l2e = 0.03608439182435161f * 1.4426950408889634f;

    const short* ywAs = reinterpret_cast<const short*>(ywA);
    const short* tS = reinterpret_cast<const short*>(textS);
    const short* tSw = tS + (((size_t)b * 64 + w * 8) * 6) * 512 + (size_t)l * 8;
    const size_t headStride = (size_t)BB * 128 * 3072;  // shorts per head

    for (int kp = 0; kp < 6; ++kp) {
        // ---- stage the head-pair's A-frags into LDS (all waves share) ----
        const size_t ab0_l0 =
            (((size_t)(2 * kp * BB + b) * 128 + tt) * 6) * 512;
        for (int u = tid; u < 768; u += 512) {
            const int p = u / 384;
            const int rem = u - p * 384;
            const int cc2 = rem >> 6;
            const int l2 = rem & 63;
            bfrag8 v = *reinterpret_cast<const bfrag8*>(
                ywAs + ab0_l0 + (size_t)p * headStride + cc2 * 512 + l2 * 8);
            *reinterpret_cast<bfrag8*>(&af_s[p][cc2][l2][0]) = v;
        }
        __syncthreads();  // af_s ready (also orders prev kp's lds_acc RMW)

        float cfr[2][4], ybk[2][4];
#pragma unroll
        for (int p = 0; p < 2; ++p) {
            const int k = 2 * kp + p;
            const float sk = sc_s[k] * invs_l2e;
#pragma unroll
            for (int r = 0; r < 4; ++r) {
                const float cf = sk * ymr[r];
                cfr[p][r] = cf;
                ybk[p][r] = yb_s[k][lg * 4 + r] * cf;  // pre-scaled bias
            }
        }

        // prime the textS pipeline: st=0's B-frags
        bfrag8 bfc[6];
#pragma unroll
        for (int cc = 0; cc < 6; ++cc)
            bfc[cc] = *reinterpret_cast<const bfrag8*>(tSw + cc * 512);

        float lrow[2][4] = {{0.f, 0.f, 0.f, 0.f}, {0.f, 0.f, 0.f, 0.f}};
#pragma unroll
        for (int st = 0; st < 8; ++st) {
            f32x4 av0 = zero4, av1 = zero4;
            __builtin_amdgcn_s_setprio(1);
#pragma unroll
            for (int cc = 0; cc < 6; ++cc) {
                bfrag8 a0 =
                    *reinterpret_cast<const bfrag8*>(&af_s[0][cc][l][0]);
                bfrag8 a1 =
                    *reinterpret_cast<const bfrag8*>(&af_s[1][cc][l][0]);
                av0 = __builtin_amdgcn_mfma_f32_16x16x32_bf16(a0, bfc[cc],
                                                              av0, 0, 0, 0);
                av1 = __builtin_amdgcn_mfma_f32_16x16x32_bf16(a1, bfc[cc],
                                                              av1, 0, 0, 0);
            }
            __builtin_amdgcn_s_setprio(0);
            // issue next st's textS loads; latency hides under exp VALU
            if (st < 7) {
#pragma unroll
                for (int cc = 0; cc < 6; ++cc)
                    bfc[cc] = *reinterpret_cast<const bfrag8*>(
                        tSw + ((st + 1) * 6 + cc) * 512);
            }
            // scale+mask+exp2 (masked scores exp2(0)=1 participate, as ref)
#pragma unroll
            for (int r = 0; r < 4; ++r) {
                float e0 = exp2f((av0[r] * cfr[0][r] + ybk[0][r]) * tm2r[st]);
                float e1 = exp2f((av1[r] * cfr[1][r] + ybk[1][r]) * tm2r[st]);
                av0[r] = e0;
                av1[r] = e1;
                lrow[0][r] += e0;
                lrow[1][r] += e1;
            }
            exp_buf[0][w][st][l] =
                make_uint2(pk2(av0[0], av0[1]), pk2(av0[2], av0[3]));
            exp_buf[1][w][st][l] =
                make_uint2(pk2(av1[0], av1[1]), pk2(av1[2], av1[3]));
        }

        // block-wide denominator over S=1024
#pragma unroll
        for (int d = 1; d < 16; d <<= 1)
#pragma unroll
            for (int p = 0; p < 2; ++p)
#pragma unroll
                for (int r = 0; r < 4; ++r)
                    lrow[p][r] += __shfl_xor(lrow[p][r], d);
        if (l15 == 0) {
#pragma unroll
            for (int p = 0; p < 2; ++p)
#pragma unroll
                for (int r = 0; r < 4; ++r)
                    lred[kp & 1][p][lg * 4 + r][w] = lrow[p][r];
        }
        __syncthreads();  // lred visible; all waves done reading af_s
        float rl[2][4];
#pragma unroll
        for (int p = 0; p < 2; ++p)
#pragma unroll
            for (int r = 0; r < 4; ++r) {
                const float4 v0 = *reinterpret_cast<const float4*>(
                    &lred[kp & 1][p][lg * 4 + r][0]);
                const float4 v1 = *reinterpret_cast<const float4*>(
                    &lred[kp & 1][p][lg * 4 + r][4]);
                rl[p][r] = 1.0f / (v0.x + v0.y + v0.z + v0.w + v1.x + v1.y +
                                   v1.z + v1.w);
            }
        // read exp back, normalize, accumulate (all LDS, wave-private)
#pragma unroll
        for (int st = 0; st < 8; ++st) {
            const uint2 e0 = exp_buf[0][w][st][l];
            const uint2 e1 = exp_buf[1][w][st][l];
            f32x4 cur = *reinterpret_cast<f32x4*>(&lds_acc[w][st][l][0]);
            cur[0] += unpk_lo(e0.x) * rl[0][0] + unpk_lo(e1.x) * rl[1][0];
            cur[1] += unpk_hi(e0.x) * rl[0][1] + unpk_hi(e1.x) * rl[1][1];
            cur[2] += unpk_lo(e0.y) * rl[0][2] + unpk_lo(e1.y) * rl[1][2];
            cur[3] += unpk_hi(e0.y) * rl[0][3] + unpk_hi(e1.y) * rl[1][3];
            *reinterpret_cast<f32x4*>(&lds_acc[w][st][l][0]) = cur;
        }
        // af_s overwrite at kp+1 is safe: this kp's 2nd barrier put every
        // wave past its st-loop (af_s reads); RMW above doesn't touch af_s.
    }
    __builtin_amdgcn_s_waitcnt(0);  // own-wave lds_acc writes visible

    // ---------------- context phase ----------------
    const short* tC = reinterpret_cast<const short*>(textC);
    f32x4 cacc[12];
#pragma unroll
    for (int c = 0; c < 12; ++c) cacc[c] = (f32x4){0.f, 0.f, 0.f, 0.f};

#pragma unroll
    for (int sc = 0; sc < 4; ++sc) {
        const int scg = w * 4 + sc;
        union {
            bfrag8 v8;
            unsigned u[4];
        } A;
#pragma unroll
        for (int jp = 0; jp < 4; ++jp) {
            const int s0 = scg * 32 + lg * 8 + jp * 2;
            const int reg0 = s0 >> 7, st0 = (s0 >> 4) & 7;
            const int lo0 = (s0 & 15) | ((l15 >> 2) << 4);
            const int s1 = s0 + 1;
            const int lo1 = (s1 & 15) | ((l15 >> 2) << 4);
            const int ro = l15 & 3;
            float a = lds_acc[reg0][st0][lo0][ro];
            float bb2 = lds_acc[s1 >> 7][(s1 >> 4) & 7][lo1][ro];
            A.u[jp] = pk2(a, bb2);
        }
#pragma unroll
        for (int ctt = 0; ctt < 12; ++ctt) {
            bfrag8 bf = *reinterpret_cast<const bfrag8*>(
                tC + (((size_t)b * 12 + ctt) * 32 + scg) * 512 + (size_t)l * 8);
            cacc[ctt] = __builtin_amdgcn_mfma_f32_16x16x32_bf16(
                A.v8, bf, cacc[ctt], 0, 0, 0);
        }
    }
    __syncthreads();  // all lds_acc reads done before overwrite as 'part'

    float(*part)[16][192] =
        reinterpret_cast<float(*)[16][192]>(&lds_acc[0][0][0][0]);
    if (w < 4) {
#pragma unroll
        for (int ctt = 0; ctt < 12; ++ctt)
#pragma unroll
            for (int r = 0; r < 4; ++r)
                part[w][lg * 4 + r][ctt * 16 + l15] = cacc[ctt][r];
    }
    __syncthreads();
    if (w >= 4) {
#pragma unroll
        for (int ctt = 0; ctt < 12; ++ctt)
#pragma unroll
            for (int r = 0; r < 4; ++r)
                part[w - 4][lg * 4 + r][ctt * 16 + l15] += cacc[ctt][r];
    }
    __syncthreads();

    // epilogue: out[b,c,t0..t0+15] = y + ctx[t][c%192] + ge[b,c]
    const float* yb_ = y + (size_t)b * CC * TT;
    float* ob = out + (size_t)b * CC * TT;
    const float* geb = ge + b * CC;
    for (int c = tid; c < CC; c += 512) {
        const float gev = geb[c];
        const int cm = c % CT;
        const float4* ysrc =
            reinterpret_cast<const float4*>(yb_ + (size_t)c * TT + t0);
        float4* od = reinterpret_cast<float4*>(ob + (size_t)c * TT + t0);
#pragma unroll
        for (int i4 = 0; i4 < 4; ++i4) {
            float4 v = ysrc[i4];
            const int row = i4 * 4;
            v.x += part[0][row + 0][cm] + part[1][row + 0][cm] +
                   part[2][row + 0][cm] + part[3][row + 0][cm] + gev;
            v.y += part[0][row + 1][cm] + part[1][row + 1][cm] +
                   part[2][row + 1][cm] + part[3][row + 1][cm] + gev;
            v.z += part[0][row + 2][cm] + part[1][row + 2][cm] +
                   part[2][row + 2][cm] + part[3][row + 2][cm] + gev;
            v.w += part[0][row + 3][cm] + part[1][row + 3][cm] +
                   part[2][row + 3][cm] + part[3][row + 3][cm] + gev;
            od[i4] = v;
        }
    }
}

// ---------------------------------------------------------------------------
extern "C" void kernel_launch(void* const* d_in, const int* in_sizes, int n_in,
                              void* d_out, int out_size, void* d_ws,
                              size_t ws_size, hipStream_t stream) {
    const float* y      = (const float*)d_in[0];
    const float* ymask  = (const float*)d_in[1];
    const float* text   = (const float*)d_in[2];
    const float* tmask  = (const float*)d_in[3];
    const float* ge     = (const float*)d_in[4];
    const float* W      = (const float*)d_in[5];
    const float* bias   = (const float*)d_in[6];
    const float* scale  = (const float*)d_in[7];
    float* out = (float*)d_out;

    // workspace carve-up (bytes)
    char* ws = (char*)d_ws;
    __hip_bfloat16* ywA   = (__hip_bfloat16*)ws;                 // 37,748,736
    float*          ybws  = (float*)(ws + 37748736);             //    393,216
    __hip_bfloat16* textS = (__hip_bfloat16*)(ws + 38141952);    //  1,572,864
    __hip_bfloat16* textC = (__hip_bfloat16*)(ws + 39714816);    //  1,572,864
    __hip_bfloat16* yP    = (__hip_bfloat16*)(ws + 58064896);    // 12,582,912
    __hip_bfloat16* WP    = (__hip_bfloat16*)(ws + 70647808);    //  3,538,944

    k_pack_all<<<512, 256, 0, stream>>>(text, W, y, bias, textS, textC, WP,
                                        yP, ybws);
    k_yw_mfma<<<1536, 256, 0, stream>>>(yP, WP, ywA);
    k_attn_fused<<<512, 512, 0, stream>>>(ymask, tmask, scale, ywA, ybws,
                                          textS, textC, y, ge, out);
}